// Round 1
// baseline (375.164 us; speedup 1.0000x reference)
//
#include <hip/hip_runtime.h>
#include <cstdint>

// ---------------------------------------------------------------------------
// GQA cross-attention, bf16-MFMA pipeline:
//   cast -> Wt transposes -> QKV GEMMs (fp32 out) -> RoPE/repack (bf16)
//   -> flash attention (bf16 MFMA, fp32 softmax) -> output GEMM (fp32 out)
// ---------------------------------------------------------------------------

typedef __bf16 bf16x8 __attribute__((ext_vector_type(8)));
typedef float f32x4 __attribute__((ext_vector_type(4)));

#define MFMA16(a, b, c) __builtin_amdgcn_mfma_f32_16x16x32_bf16((a), (b), (c), 0, 0, 0)

constexpr int Bc = 2, TQc = 2048, TKc = 2048, Dc = 1024, Hc = 16, Gc = 4, HDc = 64;

__device__ __forceinline__ ushort f2bf(float x) {  // RNE f32 -> bf16 bits
  uint32_t u = __builtin_bit_cast(uint32_t, x);
  u += 0x7fffu + ((u >> 16) & 1u);
  return (ushort)(u >> 16);
}

__device__ __forceinline__ void async_lds16(void* lds, const void* g) {
  // wave-uniform LDS base; lane i lands at base + 16*i (guide §5)
  __builtin_amdgcn_global_load_lds((const __attribute__((address_space(1))) uint32_t*)g,
                                   (__attribute__((address_space(3))) uint32_t*)lds,
                                   16, 0, 0);
}

// ---------------- elementwise f32 -> bf16 cast (vectorized x4) -------------
__global__ __launch_bounds__(256) void cast_bf16_k(const float* __restrict__ s,
                                                   ushort* __restrict__ d, int n4) {
  int i = blockIdx.x * 256 + threadIdx.x;
  if (i >= n4) return;
  float4 v = reinterpret_cast<const float4*>(s)[i];
  ushort4 o;
  o.x = f2bf(v.x); o.y = f2bf(v.y); o.z = f2bf(v.z); o.w = f2bf(v.w);
  reinterpret_cast<ushort4*>(d)[i] = o;
}

// ---------------- W [R][C] f32  ->  Wt [C][R] bf16 (64x64 LDS tiles) -------
__global__ __launch_bounds__(256) void wtrans_k(const float* __restrict__ src,
                                                ushort* __restrict__ dst, int R, int C) {
  __shared__ float t[64][65];
  int r0 = blockIdx.y * 64, c0 = blockIdx.x * 64;
  int tx = threadIdx.x & 63, ty = threadIdx.x >> 6;
#pragma unroll
  for (int i = 0; i < 16; ++i) {
    int r = i * 4 + ty;
    t[r][tx] = src[(size_t)(r0 + r) * C + c0 + tx];
  }
  __syncthreads();
#pragma unroll
  for (int i = 0; i < 16; ++i) {
    int c = i * 4 + ty;
    dst[(size_t)(c0 + c) * R + r0 + tx] = f2bf(t[tx][c]);
  }
}

// ------- v f32 [b][t][g*64+d] -> Vt bf16 [b][g][d][t]  (PV B-operand) ------
__global__ __launch_bounds__(256) void vtrans_k(const float* __restrict__ v,
                                                ushort* __restrict__ Vt) {
  __shared__ float t[64][65];
  int t0 = blockIdx.x * 64, g = blockIdx.y, b = blockIdx.z;
  int tx = threadIdx.x & 63, ty = threadIdx.x >> 6;
#pragma unroll
  for (int i = 0; i < 16; ++i) {
    int tl = i * 4 + ty;
    t[tl][tx] = v[((size_t)b * TKc + t0 + tl) * (Gc * HDc) + g * HDc + tx];
  }
  __syncthreads();
#pragma unroll
  for (int i = 0; i < 16; ++i) {
    int dd = i * 4 + ty;
    Vt[((size_t)(b * Gc + g) * HDc + dd) * TKc + t0 + tx] = f2bf(t[tx][dd]);
  }
}

// ------- RoPE + repack: q f32 [b][t][h*64+d] -> Qb bf16 [b][h][t][d] -------
__global__ __launch_bounds__(256) void ropeq_k(const float* __restrict__ q,
                                               ushort* __restrict__ Qb) {
  int idx = blockIdx.x * 256 + threadIdx.x;  // i(5) t(11) h(4) b(1)
  int i = idx & 31;
  int t = (idx >> 5) & (TQc - 1);
  int h = (idx >> 16) & (Hc - 1);
  int b = idx >> 20;
  float ang = (float)t * expf(-0.28782313662425572f * (float)i);  // -ln(1e4)/32
  float sn, cs;
  sincosf(ang, &sn, &cs);
  float2 x = *reinterpret_cast<const float2*>(&q[((size_t)b * TQc + t) * Dc + h * HDc + 2 * i]);
  ushort2 o;
  o.x = f2bf(x.x * cs - x.y * sn);
  o.y = f2bf(x.x * sn + x.y * cs);
  *reinterpret_cast<ushort2*>(&Qb[(((size_t)(b * Hc + h)) * TQc + t) * HDc + 2 * i]) = o;
}

__global__ __launch_bounds__(256) void ropek_k(const float* __restrict__ k,
                                               ushort* __restrict__ Kb) {
  int idx = blockIdx.x * 256 + threadIdx.x;  // i(5) t(11) g(2) b(1)
  int i = idx & 31;
  int t = (idx >> 5) & (TKc - 1);
  int g = (idx >> 16) & (Gc - 1);
  int b = idx >> 18;
  float ang = (float)t * expf(-0.28782313662425572f * (float)i);
  float sn, cs;
  sincosf(ang, &sn, &cs);
  float2 x = *reinterpret_cast<const float2*>(&k[((size_t)b * TKc + t) * (Gc * HDc) + g * HDc + 2 * i]);
  ushort2 o;
  o.x = f2bf(x.x * cs - x.y * sn);
  o.y = f2bf(x.x * sn + x.y * cs);
  *reinterpret_cast<ushort2*>(&Kb[(((size_t)(b * Gc + g)) * TKc + t) * HDc + 2 * i]) = o;
}

// ------- C[M][N] f32 = A[M][K]bf16 * Bt[N][K]bf16^T + bias[N] --------------
// 128x128 tile, BK=32, 4 waves (2x2), global_load_lds width-16 staging.
__global__ __launch_bounds__(256) void gemm_bt_bias(const ushort* __restrict__ A,
                                                    const ushort* __restrict__ Bt,
                                                    const float* __restrict__ bias,
                                                    float* __restrict__ C,
                                                    int M, int N, int K) {
  __shared__ __attribute__((aligned(16))) ushort sA[128 * 32];
  __shared__ __attribute__((aligned(16))) ushort sB[128 * 32];
  const int tid = threadIdx.x;
  const int lane = tid & 63, wid = tid >> 6;
  const int l15 = lane & 15, l4 = lane >> 4;
  const int m0 = blockIdx.y * 128, n0 = blockIdx.x * 128;
  const int wr = (wid >> 1) * 64, wc = (wid & 1) * 64;

  const f32x4 z = {0.f, 0.f, 0.f, 0.f};
  f32x4 acc[4][4];
#pragma unroll
  for (int mi = 0; mi < 4; ++mi)
#pragma unroll
    for (int ni = 0; ni < 4; ++ni) acc[mi][ni] = z;

  for (int k0 = 0; k0 < K; k0 += 32) {
#pragma unroll
    for (int i = 0; i < 2; ++i) {
      int c = wid * 2 + i;            // 1KB chunk index (8 per tile)
      int tb = c * 1024 + lane * 16;  // byte within tile; 64B per row (BK*2)
      int row = tb >> 6;
      int cole = (tb & 63) >> 1;
      async_lds16((char*)sA + c * 1024, A + (size_t)(m0 + row) * K + k0 + cole);
      async_lds16((char*)sB + c * 1024, Bt + (size_t)(n0 + row) * K + k0 + cole);
    }
    __syncthreads();
    bf16x8 af[4], bfr[4];
#pragma unroll
    for (int mi = 0; mi < 4; ++mi)
      af[mi] = *reinterpret_cast<const bf16x8*>(&sA[(wr + mi * 16 + l15) * 32 + l4 * 8]);
#pragma unroll
    for (int ni = 0; ni < 4; ++ni)
      bfr[ni] = *reinterpret_cast<const bf16x8*>(&sB[(wc + ni * 16 + l15) * 32 + l4 * 8]);
#pragma unroll
    for (int mi = 0; mi < 4; ++mi)
#pragma unroll
      for (int ni = 0; ni < 4; ++ni)
        acc[mi][ni] = MFMA16(af[mi], bfr[ni], acc[mi][ni]);
    __syncthreads();
  }

#pragma unroll
  for (int mi = 0; mi < 4; ++mi)
#pragma unroll
    for (int ni = 0; ni < 4; ++ni) {
      int col = n0 + wc + ni * 16 + l15;
      float bv = bias[col];
      int rowb = m0 + wr + mi * 16 + l4 * 4;  // D: row=(l>>4)*4+r, col=l&15
#pragma unroll
      for (int r = 0; r < 4; ++r)
        C[(size_t)(rowb + r) * N + col] = acc[mi][ni][r] + bv;
    }
}

// ------- flash attention: Qb[b][h][t][64], Kb[b][g][t][64], Vt[b][g][64][t]
// 4 independent waves/block, 16 q-rows/wave, KV tiles of 64, online softmax.
__global__ __launch_bounds__(256) void attn_k(const ushort* __restrict__ Qg,
                                              const ushort* __restrict__ Kg,
                                              const ushort* __restrict__ Vg,
                                              ushort* __restrict__ Ob) {
  __shared__ __attribute__((aligned(16))) ushort sP[4][16 * 64];  // per-wave P
  const int lane = threadIdx.x & 63, wid = threadIdx.x >> 6;
  const int l15 = lane & 15, l4 = lane >> 4;
  const int b = blockIdx.z, h = blockIdx.y, g = h >> 2;  // H/G = 4
  const int q0 = blockIdx.x * 64 + wid * 16;
  const ushort* Qp = Qg + ((size_t)(b * Hc + h)) * TQc * HDc;
  const ushort* Kp = Kg + ((size_t)(b * Gc + g)) * TKc * HDc;
  const ushort* Vp = Vg + ((size_t)(b * Gc + g)) * HDc * TKc;
  char* pb = (char*)&sP[wid][0];

  bf16x8 aq[2];  // Q hoisted to registers: A[m=l15][k=l4*8+j (+32)]
  aq[0] = *reinterpret_cast<const bf16x8*>(Qp + (size_t)(q0 + l15) * HDc + l4 * 8);
  aq[1] = *reinterpret_cast<const bf16x8*>(Qp + (size_t)(q0 + l15) * HDc + 32 + l4 * 8);

  float mr[4] = {-INFINITY, -INFINITY, -INFINITY, -INFINITY};
  float lr[4] = {0.f, 0.f, 0.f, 0.f};
  const f32x4 z = {0.f, 0.f, 0.f, 0.f};
  f32x4 accO[4] = {z, z, z, z};

  for (int kt = 0; kt < TKc / 64; ++kt) {
    f32x4 s[4] = {z, z, z, z};
    const ushort* Kt = Kp + (size_t)kt * 64 * HDc;
#pragma unroll
    for (int nf = 0; nf < 4; ++nf) {  // B[k=d][n=key]: K rows are contiguous
      const ushort* kr = Kt + (size_t)(nf * 16 + l15) * HDc + l4 * 8;
      s[nf] = MFMA16(aq[0], *reinterpret_cast<const bf16x8*>(kr), s[nf]);
      s[nf] = MFMA16(aq[1], *reinterpret_cast<const bf16x8*>(kr + 32), s[nf]);
    }
#pragma unroll
    for (int nf = 0; nf < 4; ++nf) s[nf] *= 0.125f;  // 1/sqrt(64)

    float sc[4];
#pragma unroll
    for (int r = 0; r < 4; ++r) {  // row = l4*4+r; reduce across 16 cols/lanes
      float rm = fmaxf(fmaxf(s[0][r], s[1][r]), fmaxf(s[2][r], s[3][r]));
#pragma unroll
      for (int off = 1; off < 16; off <<= 1) rm = fmaxf(rm, __shfl_xor(rm, off));
      float mnew = fmaxf(mr[r], rm);
      sc[r] = expf(mr[r] - mnew);
      mr[r] = mnew;
      float ps = 0.f;
#pragma unroll
      for (int nf = 0; nf < 4; ++nf) {
        float p = expf(s[nf][r] - mnew);
        s[nf][r] = p;
        ps += p;
      }
#pragma unroll
      for (int off = 1; off < 16; off <<= 1) ps += __shfl_xor(ps, off);
      lr[r] = lr[r] * sc[r] + ps;
    }
#pragma unroll
    for (int df = 0; df < 4; ++df) {
      accO[df][0] *= sc[0]; accO[df][1] *= sc[1];
      accO[df][2] *= sc[2]; accO[df][3] *= sc[3];
    }
    // P (D-layout) -> LDS, XOR-swizzled rows (guide §6 G4)
#pragma unroll
    for (int r = 0; r < 4; ++r) {
      int row = l4 * 4 + r;
      int rx = (row & 7) << 4;
#pragma unroll
      for (int nf = 0; nf < 4; ++nf) {
        int byte = row * 128 + (((nf * 16 + l15) * 2) ^ rx);
        *(ushort*)(pb + byte) = f2bf(s[nf][r]);
      }
    }
    __syncthreads();
    // PV: A = P[q=l15][key], B = Vt[d][key] (contiguous 16B global reads)
#pragma unroll
    for (int df = 0; df < 4; ++df) {
#pragma unroll
      for (int kk = 0; kk < 2; ++kk) {
        int byte = l15 * 128 + (((kk * 32 + l4 * 8) * 2) ^ ((l15 & 7) << 4));
        bf16x8 ap = *reinterpret_cast<const bf16x8*>(pb + byte);
        const ushort* vr = Vp + (size_t)(df * 16 + l15) * TKc + kt * 64 + kk * 32 + l4 * 8;
        accO[df] = MFMA16(ap, *reinterpret_cast<const bf16x8*>(vr), accO[df]);
      }
    }
    __syncthreads();
  }
#pragma unroll
  for (int df = 0; df < 4; ++df) {
#pragma unroll
    for (int r = 0; r < 4; ++r) {
      int row = q0 + l4 * 4 + r;
      int col = h * HDc + df * 16 + l15;
      Ob[((size_t)b * TQc + row) * Dc + col] = f2bf(accO[df][r] / lr[r]);
    }
  }
}

// ---------------------------------------------------------------------------
extern "C" void kernel_launch(void* const* d_in, const int* in_sizes, int n_in,
                              void* d_out, int out_size, void* d_ws, size_t ws_size,
                              hipStream_t stream) {
  const float* X  = (const float*)d_in[0];
  const float* E  = (const float*)d_in[1];
  const float* Wq = (const float*)d_in[2];
  const float* bq = (const float*)d_in[3];
  const float* Wk = (const float*)d_in[4];
  const float* bk = (const float*)d_in[5];
  const float* Wv = (const float*)d_in[6];
  const float* bv = (const float*)d_in[7];
  const float* Wo = (const float*)d_in[8];
  const float* bo = (const float*)d_in[9];
  float* out = (float*)d_out;
  char* ws = (char*)d_ws;

  const size_t MB = 1ull << 20;
  if (ws_size < 58 * MB) return;  // tripwire: reproduces stub failure signature

  ushort* Xb  = (ushort*)(ws + 0 * MB);   // [4096][1024] bf16
  ushort* Eb  = (ushort*)(ws + 8 * MB);   // [4096][1024]
  ushort* Wqt = (ushort*)(ws + 16 * MB);  // [1024][1024]
  ushort* Wkt = (ushort*)(ws + 18 * MB);  // [256][1024]
  ushort* Wvt = (ushort*)(ws + 19 * MB);  // [256][1024]
  ushort* Wot = (ushort*)(ws + 20 * MB);  // [1024][1024]
  ushort* Qb  = (ushort*)(ws + 22 * MB);  // [2][16][2048][64]
  ushort* Kb  = (ushort*)(ws + 30 * MB);  // [2][4][2048][64]
  ushort* Vt  = (ushort*)(ws + 32 * MB);  // [2][4][64][2048]
  float*  qf  = (float*)(ws + 34 * MB);   // [2][2048][1024] f32 (16MB)
  ushort* Ob  = (ushort*)(ws + 34 * MB);  // aliases qf (dead after ropeq)
  float*  kf  = (float*)(ws + 50 * MB);   // [2][2048][256] f32
  float*  vf  = (float*)(ws + 54 * MB);   // [2][2048][256] f32

  // 1. casts
  cast_bf16_k<<<4096, 256, 0, stream>>>(X, Xb, (Bc * TQc * Dc) / 4);
  cast_bf16_k<<<4096, 256, 0, stream>>>(E, Eb, (Bc * TKc * Dc) / 4);
  // 2. weight transposes ([K][N] -> [N][K] bf16)
  wtrans_k<<<dim3(16, 16), 256, 0, stream>>>(Wq, Wqt, Dc, Dc);
  wtrans_k<<<dim3(4, 16), 256, 0, stream>>>(Wk, Wkt, Dc, Gc * HDc);
  wtrans_k<<<dim3(4, 16), 256, 0, stream>>>(Wv, Wvt, Dc, Gc * HDc);
  wtrans_k<<<dim3(16, 16), 256, 0, stream>>>(Wo, Wot, Dc, Dc);
  // 3. projections
  gemm_bt_bias<<<dim3(8, 32), 256, 0, stream>>>(Xb, Wqt, bq, qf, Bc * TQc, Dc, Dc);
  gemm_bt_bias<<<dim3(2, 32), 256, 0, stream>>>(Eb, Wkt, bk, kf, Bc * TKc, Gc * HDc, Dc);
  gemm_bt_bias<<<dim3(2, 32), 256, 0, stream>>>(Eb, Wvt, bv, vf, Bc * TKc, Gc * HDc, Dc);
  // 4. RoPE + repack to attention layouts
  ropeq_k<<<(Bc * Hc * TQc * 32) / 256, 256, 0, stream>>>(qf, Qb);
  ropek_k<<<(Bc * Gc * TKc * 32) / 256, 256, 0, stream>>>(kf, Kb);
  vtrans_k<<<dim3(TKc / 64, Gc, Bc), 256, 0, stream>>>(vf, Vt);
  // 5. attention  (Ob overwrites qf region — qf is dead by now)
  attn_k<<<dim3(TQc / 64, Hc, Bc), 256, 0, stream>>>(Qb, Kb, Vt, Ob);
  // 6. output projection
  gemm_bt_bias<<<dim3(8, 32), 256, 0, stream>>>(Ob, Wot, bo, out, Bc * TQc, Dc, Dc);
}